// Round 11
// baseline (117.451 us; speedup 1.0000x reference)
//
#include <hip/hip_runtime.h>

// TaylorFeatureMap: x (2,16,2048,64) fp32 -> out (2,16,2048,2145) fp32
// Row layout per vector v:
//   [0]        = 1
//   [1..64]    = x[i] / 64^0.25
//   [65..128]  = x[i]^2 / (8*sqrt(2))
//   [129..2144]= x[i]*x[j] / 8, (i,j) = triu_indices(64, k=1) row-major
//
// R10: BARRIER-FREE at R2's occupancy. Same compute phase and same
// 4-wave/256-thread blocks as R2 (16 waves/CU), but each wave stores its
// OWN row, so there is no inter-wave LDS sharing and the __syncthreads is
// deleted outright. Waves flow compute->store independently and mutually
// desynchronize, keeping the store pipe fed during compute windows (the
// last untested mechanism behind the 5.1 vs 6.6 TB/s gap; R5's zero-barrier
// test was confounded by 4-waves/CU occupancy collapse).
// Per-row base = row*2145 floats (4B-aligned only) -> head scalars to the
// 128B boundary, aligned float4 body (LDS side lands 16B-aligned
// automatically: wave*2145+head == row+head == 0 mod 4), scalar tail.

#define D 64
#define ROW 2145
#define OFFD_BASE 129
#define RPB 4                      // rows per block (= waves per block)

__global__ __launch_bounds__(256) void taylor_fm_kernel(
    const float* __restrict__ x, float* __restrict__ out) {
    __shared__ __align__(16) float buf[RPB * ROW];   // 34,320 B

    const int wave = threadIdx.x >> 6;
    const int lane = threadIdx.x & 63;
    const int row  = blockIdx.x * RPB + wave;

    const float xl = x[(size_t)row * D + lane];

    const float inv_rrd   = 0.35355339059327373f;   // 1/64^0.25
    const float inv_rd_r2 = 0.08838834764831845f;   // 1/(8*sqrt(2))

    float* brow = buf + wave * ROW;
    if (lane == 0) brow[0] = 1.0f;
    brow[1 + lane]  = xl * inv_rrd;
    brow[65 + lane] = xl * xl * inv_rd_r2;

    // Pre-scale by exact pow2 1/8 so (x_i/8)*x_j == (x_i*x_j)/8 bit-exactly.
    const float xls = xl * 0.125f;

    float* tri = brow + OFFD_BASE;
#pragma unroll
    for (int i = 0; i < 63; ++i) {
        const int Ci = (i * (127 - i)) >> 1;        // start of row i's segment
        float xi = __uint_as_float(
            __builtin_amdgcn_readlane(__float_as_uint(xls), i));
        if (lane > i) {
            tri[Ci - i - 1 + lane] = xi * xl;
        }
    }

    // NO BARRIER: this wave reads back only its own LDS writes (per-wave
    // in-order DS execution; verified correct in R5).

    float* orow = out + (size_t)row * ROW;
    const int head = (32 - (row & 31)) & 31;        // floats to 128B boundary
    if (lane < head) orow[lane] = brow[lane];

    const int nrem   = ROW - head;                  // 2114..2145
    const int nbody4 = nrem >> 2;                   // 528..536 float4
    const float4* b4 = reinterpret_cast<const float4*>(brow + head);
    float4*       o4 = reinterpret_cast<float4*>(orow + head);

    int q = lane;
#pragma unroll
    for (int k = 0; k < 8; ++k, q += 64) {          // 8*64=512 <= 528 always
        o4[q] = b4[q];
    }
    if (q < nbody4) {                               // lanes 0..23 at most
        o4[q] = b4[q];
    }

    const int tail  = nrem & 3;                     // 0..3 floats
    const int tbase = head + (nbody4 << 2);
    if (lane < tail) orow[tbase + lane] = brow[tbase + lane];
}

extern "C" void kernel_launch(void* const* d_in, const int* in_sizes, int n_in,
                              void* d_out, int out_size, void* d_ws, size_t ws_size,
                              hipStream_t stream) {
    const float* x = (const float*)d_in[0];
    float* out = (float*)d_out;
    int nrows = in_sizes[0] / D;        // 65536
    taylor_fm_kernel<<<nrows / RPB, 256, 0, stream>>>(x, out);
}